// Round 6
// baseline (339.025 us; speedup 1.0000x reference)
//
#include <hip/hip_runtime.h>
#include <type_traits>

#define NN 100000
#define NE 1600000
#define DF 128
#define NBKT 196        // ceil(100000 / 512) node buckets
#define BKT_SHIFT 9     // 512 nodes per bucket
#define EPB 6250        // edges per block in bucket passes (256 blocks * 6250 = NE)
#define NPB2 391        // nodes per block in degree passes (256 * 391 >= NN)

typedef unsigned short ushort_t;
typedef unsigned int uint_t;
typedef __bf16 bf16x8 __attribute__((ext_vector_type(8)));
typedef float f32x4 __attribute__((ext_vector_type(4)));

union ABFrag { uint4 u; bf16x8 v; ushort_t s[8]; };

__device__ __forceinline__ ushort_t f2bf(float f) {
    uint_t u;
    __builtin_memcpy(&u, &f, 4);
    uint_t rounding = 0x7FFFu + ((u >> 16) & 1u);
    u += rounding;
    return (ushort_t)(u >> 16);
}
__device__ __forceinline__ float lo_f(uint_t u) { return __uint_as_float(u << 16); }
__device__ __forceinline__ float hi_f(uint_t u) { return __uint_as_float(u & 0xffff0000u); }
__device__ __forceinline__ uint_t pack2(float a, float b) {
    return (uint_t)f2bf(a) | ((uint_t)f2bf(b) << 16);
}

// is64 detection, inlined per block (wave 0 checks odd words of first 64 ints)
__device__ __forceinline__ int detect64(const int* ei, int* s64) {
    if (threadIdx.x < 64) {
        int v = ei[threadIdx.x];
        bool ok = ((threadIdx.x & 1) == 0) || (v == 0);
        unsigned long long m = __ballot(ok);
        if (threadIdx.x == 0) *s64 = (m == 0xFFFFFFFFFFFFFFFFULL) ? 1 : 0;
    }
    __syncthreads();
    return *s64;
}

// ---------------------------------------------------------------- pass A: per-(block,bucket) histogram
__global__ __launch_bounds__(256) void k_bktcnt(const int* __restrict__ ei,
                                                int* __restrict__ M) {
    __shared__ int cnt[NBKT];
    __shared__ int s64;
    int t = threadIdx.x, blk = blockIdx.x;
    int is64 = detect64(ei, &s64);
    for (int i = t; i < NBKT; i += 256) cnt[i] = 0;
    __syncthreads();
    int e0 = blk * EPB;
    if (is64) {
        const long long* p = (const long long*)ei;
        for (int i = t; i < EPB; i += 256) {
            int d = (int)p[(size_t)NE + e0 + i];
            atomicAdd(&cnt[d >> BKT_SHIFT], 1);
        }
    } else {
        for (int i = t; i < EPB; i += 256) {
            int d = ei[NE + e0 + i];
            atomicAdd(&cnt[d >> BKT_SHIFT], 1);
        }
    }
    __syncthreads();
    for (int i = t; i < NBKT; i += 256) M[i * 256 + blk] = cnt[i];
}

// ---------------------------------------------------------------- generic column scan (gridDim = #rows)
__global__ __launch_bounds__(256) void k_colscan(int* __restrict__ M, int* __restrict__ colsum) {
    __shared__ int sm[256];
    int t = threadIdx.x, b = blockIdx.x;
    int v = M[b * 256 + t];
    sm[t] = v;
    __syncthreads();
    for (int o = 1; o < 256; o <<= 1) {
        int add = (t >= o) ? sm[t - o] : 0;
        __syncthreads();
        sm[t] += add;
        __syncthreads();
    }
    M[b * 256 + t] = sm[t] - v;  // exclusive offset of block t within row b
    if (t == 255) colsum[b] = sm[255];
}

// ---------------------------------------------------------------- scan bucket totals -> bkbase[0..NBKT]
__global__ __launch_bounds__(256) void k_bktscan(const int* __restrict__ colsum,
                                                 int* __restrict__ bkbase, int* __restrict__ rs) {
    __shared__ int sm[256];
    int t = threadIdx.x;
    int v = (t < NBKT) ? colsum[t] : 0;
    sm[t] = v;
    __syncthreads();
    for (int o = 1; o < 256; o <<= 1) {
        int add = (t >= o) ? sm[t - o] : 0;
        __syncthreads();
        sm[t] += add;
        __syncthreads();
    }
    if (t <= NBKT) bkbase[t] = sm[t] - v;  // exclusive; bkbase[NBKT] == NE
    if (t == 0) rs[NN] = NE;
}

// ---------------------------------------------------------------- scan 512 degree totals -> dbase
__global__ void k_scan512(const int* __restrict__ c2, int* __restrict__ dbase) {
    __shared__ int sm[512];
    int t = threadIdx.x;
    int v = c2[t];
    sm[t] = v;
    __syncthreads();
    for (int o = 1; o < 512; o <<= 1) {
        int add = (t >= o) ? sm[t - o] : 0;
        __syncthreads();
        sm[t] += add;
        __syncthreads();
    }
    dbase[t] = sm[t] - v;  // exclusive
}

// ---------------------------------------------------------------- pass B: scatter (src,dst) into bucket regions
__global__ __launch_bounds__(256) void k_bktscatter(const int* __restrict__ ei,
                                                    const int* __restrict__ M,
                                                    const int* __restrict__ bkbase,
                                                    uint2* __restrict__ tmp) {
    __shared__ int cur[NBKT];
    __shared__ int s64;
    int t = threadIdx.x, blk = blockIdx.x;
    int is64 = detect64(ei, &s64);
    for (int i = t; i < NBKT; i += 256) cur[i] = bkbase[i] + M[i * 256 + blk];
    __syncthreads();
    int e0 = blk * EPB;
    if (is64) {
        const long long* p = (const long long*)ei;
        for (int i = t; i < EPB; i += 256) {
            int e = e0 + i;
            int s = (int)p[e], d = (int)p[(size_t)NE + e];
            int pos = atomicAdd(&cur[d >> BKT_SHIFT], 1);
            tmp[pos] = make_uint2((uint_t)s, (uint_t)d);
        }
    } else {
        for (int i = t; i < EPB; i += 256) {
            int e = e0 + i;
            int s = ei[e], d = ei[NE + e];
            int pos = atomicAdd(&cur[d >> BKT_SHIFT], 1);
            tmp[pos] = make_uint2((uint_t)s, (uint_t)d);
        }
    }
}

// ---------------------------------------------------------------- pass C: per-bucket node sort -> rs + esrc
__global__ __launch_bounds__(256) void k_bktsort(const uint2* __restrict__ tmp,
                                                 const int* __restrict__ bkbase,
                                                 int* __restrict__ rs, int* __restrict__ esrc) {
    __shared__ int hist[512];
    __shared__ int curp[512];
    int t = threadIdx.x, b = blockIdx.x;
    int nbase = b << BKT_SHIFT;
    int bb = bkbase[b], be = bkbase[b + 1];
    hist[t] = 0;
    hist[t + 256] = 0;
    __syncthreads();
    for (int i = bb + t; i < be; i += 256)
        atomicAdd(&hist[(int)tmp[i].y - nbase], 1);
    __syncthreads();
    int ov0 = hist[t], ov1 = hist[t + 256];
    for (int o = 1; o < 512; o <<= 1) {
        int v0 = (t >= o) ? hist[t - o] : 0;
        int v1 = (t + 256 >= o) ? hist[t + 256 - o] : 0;
        __syncthreads();
        hist[t] += v0;
        hist[t + 256] += v1;
        __syncthreads();
    }
    int ex0 = bb + hist[t] - ov0;
    int ex1 = bb + hist[t + 256] - ov1;
    int n0 = nbase + t, n1 = nbase + t + 256;
    if (n0 < NN) rs[n0] = ex0;
    if (n1 < NN) rs[n1] = ex1;
    curp[t] = ex0;
    curp[t + 256] = ex1;
    __syncthreads();
    for (int i = bb + t; i < be; i += 256) {
        uint2 pr = tmp[i];
        int pos = atomicAdd(&curp[(int)pr.y - nbase], 1);
        esrc[pos] = (int)pr.x;
    }
}

// ---------------------------------------------------------------- degree pass A: per-(block,deg) counts
__global__ __launch_bounds__(256) void k_dcnt(const int* __restrict__ rs, int* __restrict__ M2) {
    __shared__ int cnt[512];
    int t = threadIdx.x, b = blockIdx.x;
    cnt[t] = 0;
    cnt[t + 256] = 0;
    __syncthreads();
    int base = b * NPB2;
    for (int i = t; i < NPB2; i += 256) {
        int n = base + i;
        if (n < NN) {
            int d = rs[n + 1] - rs[n];
            if (d > 511) d = 511;
            atomicAdd(&cnt[d], 1);
        }
    }
    __syncthreads();
    M2[t * 256 + b] = cnt[t];
    M2[(t + 256) * 256 + b] = cnt[t + 256];
}

// ---------------------------------------------------------------- degree pass B: scatter node ids by degree
__global__ __launch_bounds__(256) void k_dperm(const int* __restrict__ rs,
                                               const int* __restrict__ M2,
                                               const int* __restrict__ dbase,
                                               int* __restrict__ perm) {
    __shared__ int cur[512];
    int t = threadIdx.x, b = blockIdx.x;
    cur[t] = dbase[t] + M2[t * 256 + b];
    cur[t + 256] = dbase[t + 256] + M2[(t + 256) * 256 + b];
    __syncthreads();
    int base = b * NPB2;
    for (int i = t; i < NPB2; i += 256) {
        int n = base + i;
        if (n < NN) {
            int d = rs[n + 1] - rs[n];
            if (d > 511) d = 511;
            int pos = atomicAdd(&cur[d], 1);
            perm[pos] = n;
        }
    }
}

// ---------------------------------------------------------------- prep: cast x->xb (+zero row), pack W0, pack W1
#define CAST_B 12501
__global__ void k_prep(const float* __restrict__ x, ushort_t* __restrict__ xb,
                       const float* __restrict__ Wl0, const float* __restrict__ Wr0,
                       ushort_t* __restrict__ pw0,
                       const float* __restrict__ Wl1, const float* __restrict__ Wr1,
                       ushort_t* __restrict__ pw1) {
    const int n4 = NN * DF / 4;
    int blk = blockIdx.x, t = threadIdx.x;
    if (blk < CAST_B) {
        int i = blk * 256 + t;
        if (i < n4) {
            float4 f = ((const float4*)x)[i];
            uint2 o;
            o.x = pack2(f.x, f.y);
            o.y = pack2(f.z, f.w);
            ((uint2*)xb)[i] = o;
        } else if (i < n4 + 32) {
            ((uint2*)xb)[i] = make_uint2(0u, 0u);  // zero row NN (gather clamp target)
        }
    } else if (blk < CAST_B + 128) {
        int idx = (blk - CAST_B) * 256 + t;  // < 32768
        int j = idx & 7;
        int lane = (idx >> 3) & 63;
        int rem = idx / 512;
        int tt = rem % 8;
        int s = rem / 8;
        int quad = lane >> 4, l16 = lane & 15;
        int k = (s & 3) * 32 + quad * 8 + j;
        int n = tt * 16 + l16;
        const float* W = (s < 4) ? Wl0 : Wr0;
        pw0[idx] = f2bf(W[k * 128 + n]);
    } else {
        int idx = (blk - CAST_B - 128) * 256 + t;  // < 16384
        int j = idx & 7;
        int lane = (idx >> 3) & 63;
        int rem = idx / 512;
        int tt = rem % 8;
        int s = rem / 8;
        int quad = lane >> 4, l16 = lane & 15;
        int k = s * 32 + quad * 8 + j;
        int n = (tt & 3) * 16 + l16;
        const float* W = (tt < 4) ? Wl1 : Wr1;
        pw1[idx] = f2bf(W[k * 64 + n]);
    }
}

// ---------------------------------------------------------------- layer-0 mean aggregation (degree-sorted)
// 4 nodes per wave (16-lane groups) via perm: co-scheduled nodes have ~equal degree.
// 16 row-loads in flight per wave. xb row NN is zero.
__global__ __launch_bounds__(256) void k_agg0(const ushort_t* __restrict__ xb,
                                              const int* __restrict__ rs,
                                              const int* __restrict__ esrc,
                                              const int* __restrict__ perm,
                                              ushort_t* __restrict__ outm) {
    int wv = threadIdx.x >> 6;
    int lane = threadIdx.x & 63;
    int l16 = lane & 15, quad = lane >> 4, gbase = lane & 48;
    int slot = (blockIdx.x * 4 + wv) * 4 + quad;  // NN = 6250*16 exactly
    int n = perm[slot];
    int s0 = rs[n];
    int deg = rs[n + 1] - s0;
    if (deg == 0) s0 = 0;  // keep index reads in-bounds; values unused
    int md = deg;
    md = max(md, __shfl_xor(md, 16));
    md = max(md, __shfl_xor(md, 32));
    float acc[8] = {0.f, 0.f, 0.f, 0.f, 0.f, 0.f, 0.f, 0.f};
    const ushort_t* fb = xb + l16 * 8;
    int clampIdx = (deg > 0) ? deg - 1 : 0;
    for (int c = 0; c < md; c += 16) {
        int ii = c + l16;
        if (ii > clampIdx) ii = clampIdx;
        int my = esrc[s0 + ii];
        uint4 v[16];
#pragma unroll
        for (int e = 0; e < 16; e++) {
            int r = __shfl(my, gbase + e);
            r = (c + e < deg) ? r : NN;  // row NN is zero
            v[e] = *(const uint4*)(fb + (size_t)r * DF);
        }
#pragma unroll
        for (int e = 0; e < 16; e++) {
            acc[0] += lo_f(v[e].x); acc[1] += hi_f(v[e].x);
            acc[2] += lo_f(v[e].y); acc[3] += hi_f(v[e].y);
            acc[4] += lo_f(v[e].z); acc[5] += hi_f(v[e].z);
            acc[6] += lo_f(v[e].w); acc[7] += hi_f(v[e].w);
        }
    }
    float inv = 1.0f / (float)(deg > 0 ? deg : 1);
    uint4 o;
    o.x = pack2(acc[0] * inv, acc[1] * inv);
    o.y = pack2(acc[2] * inv, acc[3] * inv);
    o.z = pack2(acc[4] * inv, acc[5] * inv);
    o.w = pack2(acc[6] * inv, acc[7] * inv);
    *(uint4*)(outm + (size_t)n * DF + l16 * 8) = o;
}

// ---------------------------------------------------------------- layer-0 MFMA GEMM (K=256 concat)
// h[NN,128] = relu([mean | xb] @ [Wl0; Wr0] + b)
__global__ __launch_bounds__(256) void k_gemm0(const ushort_t* __restrict__ A0,
                                               const ushort_t* __restrict__ A1,
                                               const ushort_t* __restrict__ Wpk,
                                               const float* __restrict__ bias,
                                               ushort_t* __restrict__ out) {
    int warp = threadIdx.x >> 6;
    int lane = threadIdx.x & 63;
    int quad = lane >> 4;
    int l16 = lane & 15;
    int m0 = blockIdx.x * 64 + warp * 16;

    int rowA = m0 + l16;
    if (rowA >= NN) rowA = NN - 1;
    const int kofs = quad * 8;

    f32x4 acc[8];
#pragma unroll
    for (int t = 0; t < 8; t++) acc[t] = (f32x4){0.f, 0.f, 0.f, 0.f};

#pragma unroll
    for (int s = 0; s < 8; s++) {
        const ushort_t* Ab = (s < 4) ? A0 : A1;
        int kk = (s & 3) * 32 + kofs;
        ABFrag a;
        a.u = *(const uint4*)(Ab + (size_t)rowA * DF + kk);
#pragma unroll
        for (int t = 0; t < 8; t++) {
            ABFrag b;
            b.u = *(const uint4*)(Wpk + ((size_t)(s * 8 + t) * 64 + lane) * 8);
            acc[t] = __builtin_amdgcn_mfma_f32_16x16x32_bf16(a.v, b.v, acc[t], 0, 0, 0);
        }
    }

#pragma unroll
    for (int t = 0; t < 8; t++) {
        int col = t * 16 + l16;
        float bv = bias[col];
#pragma unroll
        for (int r = 0; r < 4; r++) {
            int row = m0 + quad * 4 + r;
            if (row < NN) {
                float v = fmaxf(acc[t][r] + bv, 0.f);
                out[(size_t)row * DF + col] = f2bf(v);
            }
        }
    }
}

// ---------------------------------------------------------------- layer-1 MFMA GEMM (K=128, dual out)
// [t|r] = h @ [Wl1|Wr1]; t -> bf16 tbuf, r + bias -> f32 rbuf. Also zeros tbuf row NN.
__global__ __launch_bounds__(256) void k_gemm2(const ushort_t* __restrict__ A,
                                               const ushort_t* __restrict__ Wpk,
                                               const float* __restrict__ bias,
                                               ushort_t* __restrict__ tbuf,
                                               float* __restrict__ rbuf) {
    int warp = threadIdx.x >> 6;
    int lane = threadIdx.x & 63;
    int quad = lane >> 4;
    int l16 = lane & 15;
    int m0 = blockIdx.x * 64 + warp * 16;

    int rowA = m0 + l16;
    if (rowA >= NN) rowA = NN - 1;
    const int kofs = quad * 8;

    f32x4 acc[8];
#pragma unroll
    for (int t = 0; t < 8; t++) acc[t] = (f32x4){0.f, 0.f, 0.f, 0.f};

#pragma unroll
    for (int s = 0; s < 4; s++) {
        int kk = s * 32 + kofs;
        ABFrag a;
        a.u = *(const uint4*)(A + (size_t)rowA * DF + kk);
#pragma unroll
        for (int t = 0; t < 8; t++) {
            ABFrag b;
            b.u = *(const uint4*)(Wpk + ((size_t)(s * 8 + t) * 64 + lane) * 8);
            acc[t] = __builtin_amdgcn_mfma_f32_16x16x32_bf16(a.v, b.v, acc[t], 0, 0, 0);
        }
    }

#pragma unroll
    for (int t = 0; t < 8; t++) {
        int cc = (t & 3) * 16 + l16;
        if (t < 4) {
#pragma unroll
            for (int r = 0; r < 4; r++) {
                int row = m0 + quad * 4 + r;
                if (row < NN) tbuf[(size_t)row * 64 + cc] = f2bf(acc[t][r]);
            }
        } else {
            float bv = bias[cc];
#pragma unroll
            for (int r = 0; r < 4; r++) {
                int row = m0 + quad * 4 + r;
                if (row < NN) rbuf[(size_t)row * 64 + cc] = acc[t][r] + bv;
            }
        }
    }
    if (blockIdx.x == 0 && threadIdx.x < 32)
        ((uint_t*)(tbuf + (size_t)NN * 64))[threadIdx.x] = 0u;  // zero row NN for agg2 clamp
}

// ---------------------------------------------------------------- layer-1 final: out = mean(gather(t)) + r
// 8 nodes per wave (8-lane groups) via perm; t rows 128 B; 8 row-load insts in flight.
__global__ __launch_bounds__(256) void k_agg2(const ushort_t* __restrict__ tbuf,
                                              const float* __restrict__ rbuf,
                                              const int* __restrict__ rs,
                                              const int* __restrict__ esrc,
                                              const int* __restrict__ perm,
                                              float* __restrict__ out) {
    int wv = threadIdx.x >> 6;
    int lane = threadIdx.x & 63;
    int li = lane & 7;
    int gbase = lane & 56;
    int slot = (blockIdx.x * 4 + wv) * 8 + (lane >> 3);  // NN = 3125*32 exactly
    int n = perm[slot];
    int s0 = rs[n];
    int deg = rs[n + 1] - s0;
    if (deg == 0) s0 = 0;
    int md = deg;
    md = max(md, __shfl_xor(md, 8));
    md = max(md, __shfl_xor(md, 16));
    md = max(md, __shfl_xor(md, 32));
    float acc[8] = {0.f, 0.f, 0.f, 0.f, 0.f, 0.f, 0.f, 0.f};
    const ushort_t* fb = tbuf + li * 8;
    int clampIdx = (deg > 0) ? deg - 1 : 0;
    for (int c = 0; c < md; c += 8) {
        int ii = c + li;
        if (ii > clampIdx) ii = clampIdx;
        int my = esrc[s0 + ii];
        uint4 v[8];
#pragma unroll
        for (int e = 0; e < 8; e++) {
            int r = __shfl(my, gbase + e);
            r = (c + e < deg) ? r : NN;  // row NN is zero
            v[e] = *(const uint4*)(fb + (size_t)r * 64);
        }
#pragma unroll
        for (int e = 0; e < 8; e++) {
            acc[0] += lo_f(v[e].x); acc[1] += hi_f(v[e].x);
            acc[2] += lo_f(v[e].y); acc[3] += hi_f(v[e].y);
            acc[4] += lo_f(v[e].z); acc[5] += hi_f(v[e].z);
            acc[6] += lo_f(v[e].w); acc[7] += hi_f(v[e].w);
        }
    }
    float inv = 1.0f / (float)(deg > 0 ? deg : 1);
    const float4* rp = (const float4*)(rbuf + (size_t)n * 64 + li * 8);
    float4 ra = rp[0], rb = rp[1];
    float4 oa, ob;
    oa.x = acc[0] * inv + ra.x; oa.y = acc[1] * inv + ra.y;
    oa.z = acc[2] * inv + ra.z; oa.w = acc[3] * inv + ra.w;
    ob.x = acc[4] * inv + rb.x; ob.y = acc[5] * inv + rb.y;
    ob.z = acc[6] * inv + rb.z; ob.w = acc[7] * inv + rb.w;
    float4* op = (float4*)(out + (size_t)n * 64 + li * 8);
    op[0] = oa;
    op[1] = ob;
}

// ---------------------------------------------------------------- launcher
extern "C" void kernel_launch(void* const* d_in, const int* in_sizes, int n_in,
                              void* d_out, int out_size, void* d_ws, size_t ws_size,
                              hipStream_t stream) {
    const float* x   = (const float*)d_in[0];
    const int*   ei  = (const int*)d_in[1];
    const float* Wl0 = (const float*)d_in[2];
    const float* bl0 = (const float*)d_in[3];
    const float* Wr0 = (const float*)d_in[4];
    const float* Wl1 = (const float*)d_in[5];
    const float* bl1 = (const float*)d_in[6];
    const float* Wr1 = (const float*)d_in[7];
    float* out = (float*)d_out;

    char* ws = (char*)d_ws;
    size_t off = 0;
    auto alloc = [&](size_t b) {
        size_t o = off;
        off += (b + 255) & ~(size_t)255;
        return o;
    };
    int* rs      = (int*)(ws + alloc((size_t)(NN + 1) * 4));
    int* M       = (int*)(ws + alloc((size_t)NBKT * 256 * 4));
    int* colsum  = (int*)(ws + alloc((size_t)NBKT * 4));
    int* bkbase  = (int*)(ws + alloc((size_t)(NBKT + 1) * 4));
    int* M2      = (int*)(ws + alloc((size_t)512 * 256 * 4));
    int* colsum2 = (int*)(ws + alloc((size_t)512 * 4));
    int* dbase   = (int*)(ws + alloc((size_t)512 * 4));
    int* perm    = (int*)(ws + alloc((size_t)NN * 4));
    int* esrc    = (int*)(ws + alloc((size_t)NE * 4));
    ushort_t* pw0  = (ushort_t*)(ws + alloc((size_t)8 * 8 * 512 * 2));
    ushort_t* pw1  = (ushort_t*)(ws + alloc((size_t)4 * 8 * 512 * 2));
    ushort_t* xb   = (ushort_t*)(ws + alloc((size_t)(NN + 1) * DF * 2));  // +1 zero row
    ushort_t* mean = (ushort_t*)(ws + alloc((size_t)NN * DF * 2));
    ushort_t* h    = (ushort_t*)(ws + alloc((size_t)NN * DF * 2));
    ushort_t* tbuf = (ushort_t*)(ws + alloc((size_t)(NN + 1) * 64 * 2));  // +1 zero row
    // Aliases (stream-ordered lifetimes):
    //   tmp (12.8MB, bktscatter->bktsort) on mean (first written by k_agg0, later)
    //   rbuf (25.6MB, gemm2->agg2)        on mean (dead after gemm0 reads it)
    uint2* tmp = (uint2*)mean;
    float* rbuf = (float*)mean;

    k_bktcnt<<<256, 256, 0, stream>>>(ei, M);
    k_colscan<<<NBKT, 256, 0, stream>>>(M, colsum);
    k_bktscan<<<1, 256, 0, stream>>>(colsum, bkbase, rs);
    k_bktscatter<<<256, 256, 0, stream>>>(ei, M, bkbase, tmp);
    k_bktsort<<<NBKT, 256, 0, stream>>>(tmp, bkbase, rs, esrc);
    k_dcnt<<<256, 256, 0, stream>>>(rs, M2);
    k_colscan<<<512, 256, 0, stream>>>(M2, colsum2);
    k_scan512<<<1, 512, 0, stream>>>(colsum2, dbase);
    k_dperm<<<256, 256, 0, stream>>>(rs, M2, dbase, perm);
    k_prep<<<CAST_B + 128 + 64, 256, 0, stream>>>(x, xb, Wl0, Wr0, pw0, Wl1, Wr1, pw1);

    k_agg0<<<NN / 16, 256, 0, stream>>>(xb, rs, esrc, perm, mean);
    k_gemm0<<<(NN + 63) / 64, 256, 0, stream>>>(mean, xb, pw0, bl0, h);
    k_gemm2<<<(NN + 63) / 64, 256, 0, stream>>>(h, pw1, bl1, tbuf, rbuf);
    k_agg2<<<NN / 32, 256, 0, stream>>>(tbuf, rbuf, rs, esrc, perm, out);
}

// Round 7
// 316.169 us; speedup vs baseline: 1.0723x; 1.0723x over previous
//
#include <hip/hip_runtime.h>
#include <type_traits>

#define NN 100000
#define NE 1600000
#define DF 128
#define NBKT 196        // ceil(100000 / 512) node buckets
#define BKT_SHIFT 9     // 512 nodes per bucket
#define EPB 6250        // edges per block in bucket passes (256 blocks * 6250 = NE)
#define NPB2 391        // nodes per block in degree passes (256 * 391 >= NN)

typedef unsigned short ushort_t;
typedef unsigned int uint_t;
typedef __bf16 bf16x8 __attribute__((ext_vector_type(8)));
typedef float f32x4 __attribute__((ext_vector_type(4)));

union ABFrag { uint4 u; bf16x8 v; ushort_t s[8]; };

__device__ __forceinline__ ushort_t f2bf(float f) {
    uint_t u;
    __builtin_memcpy(&u, &f, 4);
    uint_t rounding = 0x7FFFu + ((u >> 16) & 1u);
    u += rounding;
    return (ushort_t)(u >> 16);
}
__device__ __forceinline__ float lo_f(uint_t u) { return __uint_as_float(u << 16); }
__device__ __forceinline__ float hi_f(uint_t u) { return __uint_as_float(u & 0xffff0000u); }
__device__ __forceinline__ uint_t pack2(float a, float b) {
    return (uint_t)f2bf(a) | ((uint_t)f2bf(b) << 16);
}

// is64 detection, inlined per block (wave 0 checks odd words of first 64 ints)
__device__ __forceinline__ int detect64(const int* ei, int* s64) {
    if (threadIdx.x < 64) {
        int v = ei[threadIdx.x];
        bool ok = ((threadIdx.x & 1) == 0) || (v == 0);
        unsigned long long m = __ballot(ok);
        if (threadIdx.x == 0) *s64 = (m == 0xFFFFFFFFFFFFFFFFULL) ? 1 : 0;
    }
    __syncthreads();
    return *s64;
}

// ---------------------------------------------------------------- pass A: per-(block,bucket) histogram
__global__ __launch_bounds__(256) void k_bktcnt(const int* __restrict__ ei,
                                                int* __restrict__ M) {
    __shared__ int cnt[NBKT];
    __shared__ int s64;
    int t = threadIdx.x, blk = blockIdx.x;
    int is64 = detect64(ei, &s64);
    for (int i = t; i < NBKT; i += 256) cnt[i] = 0;
    __syncthreads();
    int e0 = blk * EPB;
    if (is64) {
        const long long* p = (const long long*)ei;
        for (int i = t; i < EPB; i += 256) {
            int d = (int)p[(size_t)NE + e0 + i];
            atomicAdd(&cnt[d >> BKT_SHIFT], 1);
        }
    } else {
        for (int i = t; i < EPB; i += 256) {
            int d = ei[NE + e0 + i];
            atomicAdd(&cnt[d >> BKT_SHIFT], 1);
        }
    }
    __syncthreads();
    for (int i = t; i < NBKT; i += 256) M[i * 256 + blk] = cnt[i];
}

// ---------------------------------------------------------------- generic column scan (gridDim = #rows)
__global__ __launch_bounds__(256) void k_colscan(int* __restrict__ M, int* __restrict__ colsum) {
    __shared__ int sm[256];
    int t = threadIdx.x, b = blockIdx.x;
    int v = M[b * 256 + t];
    sm[t] = v;
    __syncthreads();
    for (int o = 1; o < 256; o <<= 1) {
        int add = (t >= o) ? sm[t - o] : 0;
        __syncthreads();
        sm[t] += add;
        __syncthreads();
    }
    M[b * 256 + t] = sm[t] - v;  // exclusive offset of block t within row b
    if (t == 255) colsum[b] = sm[255];
}

// ---------------------------------------------------------------- scan bucket totals -> bkbase[0..NBKT]
__global__ __launch_bounds__(256) void k_bktscan(const int* __restrict__ colsum,
                                                 int* __restrict__ bkbase, int* __restrict__ rs) {
    __shared__ int sm[256];
    int t = threadIdx.x;
    int v = (t < NBKT) ? colsum[t] : 0;
    sm[t] = v;
    __syncthreads();
    for (int o = 1; o < 256; o <<= 1) {
        int add = (t >= o) ? sm[t - o] : 0;
        __syncthreads();
        sm[t] += add;
        __syncthreads();
    }
    if (t <= NBKT) bkbase[t] = sm[t] - v;  // exclusive; bkbase[NBKT] == NE
    if (t == 0) rs[NN] = NE;
}

// ---------------------------------------------------------------- scan 512 degree totals -> dbase
__global__ void k_scan512(const int* __restrict__ c2, int* __restrict__ dbase) {
    __shared__ int sm[512];
    int t = threadIdx.x;
    int v = c2[t];
    sm[t] = v;
    __syncthreads();
    for (int o = 1; o < 512; o <<= 1) {
        int add = (t >= o) ? sm[t - o] : 0;
        __syncthreads();
        sm[t] += add;
        __syncthreads();
    }
    dbase[t] = sm[t] - v;  // exclusive
}

// ---------------------------------------------------------------- pass B: scatter (src,dst) into bucket regions
__global__ __launch_bounds__(256) void k_bktscatter(const int* __restrict__ ei,
                                                    const int* __restrict__ M,
                                                    const int* __restrict__ bkbase,
                                                    uint2* __restrict__ tmp) {
    __shared__ int cur[NBKT];
    __shared__ int s64;
    int t = threadIdx.x, blk = blockIdx.x;
    int is64 = detect64(ei, &s64);
    for (int i = t; i < NBKT; i += 256) cur[i] = bkbase[i] + M[i * 256 + blk];
    __syncthreads();
    int e0 = blk * EPB;
    if (is64) {
        const long long* p = (const long long*)ei;
        for (int i = t; i < EPB; i += 256) {
            int e = e0 + i;
            int s = (int)p[e], d = (int)p[(size_t)NE + e];
            int pos = atomicAdd(&cur[d >> BKT_SHIFT], 1);
            tmp[pos] = make_uint2((uint_t)s, (uint_t)d);
        }
    } else {
        for (int i = t; i < EPB; i += 256) {
            int e = e0 + i;
            int s = ei[e], d = ei[NE + e];
            int pos = atomicAdd(&cur[d >> BKT_SHIFT], 1);
            tmp[pos] = make_uint2((uint_t)s, (uint_t)d);
        }
    }
}

// ---------------------------------------------------------------- pass C: per-bucket node sort -> rs + esrc
__global__ __launch_bounds__(256) void k_bktsort(const uint2* __restrict__ tmp,
                                                 const int* __restrict__ bkbase,
                                                 int* __restrict__ rs, int* __restrict__ esrc) {
    __shared__ int hist[512];
    __shared__ int curp[512];
    int t = threadIdx.x, b = blockIdx.x;
    int nbase = b << BKT_SHIFT;
    int bb = bkbase[b], be = bkbase[b + 1];
    hist[t] = 0;
    hist[t + 256] = 0;
    __syncthreads();
    for (int i = bb + t; i < be; i += 256)
        atomicAdd(&hist[(int)tmp[i].y - nbase], 1);
    __syncthreads();
    int ov0 = hist[t], ov1 = hist[t + 256];
    for (int o = 1; o < 512; o <<= 1) {
        int v0 = (t >= o) ? hist[t - o] : 0;
        int v1 = (t + 256 >= o) ? hist[t + 256 - o] : 0;
        __syncthreads();
        hist[t] += v0;
        hist[t + 256] += v1;
        __syncthreads();
    }
    int ex0 = bb + hist[t] - ov0;
    int ex1 = bb + hist[t + 256] - ov1;
    int n0 = nbase + t, n1 = nbase + t + 256;
    if (n0 < NN) rs[n0] = ex0;
    if (n1 < NN) rs[n1] = ex1;
    curp[t] = ex0;
    curp[t + 256] = ex1;
    __syncthreads();
    for (int i = bb + t; i < be; i += 256) {
        uint2 pr = tmp[i];
        int pos = atomicAdd(&curp[(int)pr.y - nbase], 1);
        esrc[pos] = (int)pr.x;
    }
}

// ---------------------------------------------------------------- degree pass A: per-(block,deg) counts
__global__ __launch_bounds__(256) void k_dcnt(const int* __restrict__ rs, int* __restrict__ M2) {
    __shared__ int cnt[512];
    int t = threadIdx.x, b = blockIdx.x;
    cnt[t] = 0;
    cnt[t + 256] = 0;
    __syncthreads();
    int base = b * NPB2;
    for (int i = t; i < NPB2; i += 256) {
        int n = base + i;
        if (n < NN) {
            int d = rs[n + 1] - rs[n];
            if (d > 511) d = 511;
            atomicAdd(&cnt[d], 1);
        }
    }
    __syncthreads();
    M2[t * 256 + b] = cnt[t];
    M2[(t + 256) * 256 + b] = cnt[t + 256];
}

// ---------------------------------------------------------------- degree pass B: scatter node ids by degree
__global__ __launch_bounds__(256) void k_dperm(const int* __restrict__ rs,
                                               const int* __restrict__ M2,
                                               const int* __restrict__ dbase,
                                               int* __restrict__ perm) {
    __shared__ int cur[512];
    int t = threadIdx.x, b = blockIdx.x;
    cur[t] = dbase[t] + M2[t * 256 + b];
    cur[t + 256] = dbase[t + 256] + M2[(t + 256) * 256 + b];
    __syncthreads();
    int base = b * NPB2;
    for (int i = t; i < NPB2; i += 256) {
        int n = base + i;
        if (n < NN) {
            int d = rs[n + 1] - rs[n];
            if (d > 511) d = 511;
            int pos = atomicAdd(&cur[d], 1);
            perm[pos] = n;
        }
    }
}

// ---------------------------------------------------------------- prep: cast x->xb (+zero row), pack W0, pack W1
#define CAST_B 12501
__global__ void k_prep(const float* __restrict__ x, ushort_t* __restrict__ xb,
                       const float* __restrict__ Wl0, const float* __restrict__ Wr0,
                       ushort_t* __restrict__ pw0,
                       const float* __restrict__ Wl1, const float* __restrict__ Wr1,
                       ushort_t* __restrict__ pw1) {
    const int n4 = NN * DF / 4;
    int blk = blockIdx.x, t = threadIdx.x;
    if (blk < CAST_B) {
        int i = blk * 256 + t;
        if (i < n4) {
            float4 f = ((const float4*)x)[i];
            uint2 o;
            o.x = pack2(f.x, f.y);
            o.y = pack2(f.z, f.w);
            ((uint2*)xb)[i] = o;
        } else if (i < n4 + 32) {
            ((uint2*)xb)[i] = make_uint2(0u, 0u);  // zero row NN (gather clamp target)
        }
    } else if (blk < CAST_B + 128) {
        int idx = (blk - CAST_B) * 256 + t;  // < 32768
        int j = idx & 7;
        int lane = (idx >> 3) & 63;
        int rem = idx / 512;
        int tt = rem % 8;
        int s = rem / 8;
        int quad = lane >> 4, l16 = lane & 15;
        int k = (s & 3) * 32 + quad * 8 + j;
        int n = tt * 16 + l16;
        const float* W = (s < 4) ? Wl0 : Wr0;
        pw0[idx] = f2bf(W[k * 128 + n]);
    } else {
        int idx = (blk - CAST_B - 128) * 256 + t;  // < 16384
        int j = idx & 7;
        int lane = (idx >> 3) & 63;
        int rem = idx / 512;
        int tt = rem % 8;
        int s = rem / 8;
        int quad = lane >> 4, l16 = lane & 15;
        int k = s * 32 + quad * 8 + j;
        int n = (tt & 3) * 16 + l16;
        const float* W = (tt < 4) ? Wl1 : Wr1;
        pw1[idx] = f2bf(W[k * 64 + n]);
    }
}

// ---------------------------------------------------------------- layer-0 mean aggregation
// R4 load structure (4 outstanding, low VGPR) + degree-sorted perm (md ~= deg).
__global__ __launch_bounds__(256) void k_agg0(const ushort_t* __restrict__ xb,
                                              const int* __restrict__ rs,
                                              const int* __restrict__ esrc,
                                              const int* __restrict__ perm,
                                              ushort_t* __restrict__ outm) {
    int wv = threadIdx.x >> 6;
    int lane = threadIdx.x & 63;
    int l16 = lane & 15, gbase = lane & 48;
    int slot = (blockIdx.x * 4 + wv) * 4 + (lane >> 4);  // NN = 6250*16 exactly
    int n = perm[slot];
    int s0 = rs[n];
    int deg = rs[n + 1] - s0;
    if (deg == 0) s0 = 0;  // keep index reads in-bounds; values unused
    int md = deg;
    md = max(md, __shfl_xor(md, 16));
    md = max(md, __shfl_xor(md, 32));
    float acc[8] = {0.f, 0.f, 0.f, 0.f, 0.f, 0.f, 0.f, 0.f};
    const ushort_t* fb = xb + l16 * 8;
    int clampIdx = (deg > 0) ? deg - 1 : 0;
    for (int c = 0; c < md; c += 16) {
        int ii = c + l16;
        if (ii > clampIdx) ii = clampIdx;
        int my = esrc[s0 + ii];
        int lim = md - c;
        if (lim > 16) lim = 16;
        int e = 0;
        for (; e + 4 <= lim; e += 4) {
            int r0 = __shfl(my, gbase + e);
            int r1 = __shfl(my, gbase + e + 1);
            int r2 = __shfl(my, gbase + e + 2);
            int r3 = __shfl(my, gbase + e + 3);
            r0 = (c + e < deg) ? r0 : NN;
            r1 = (c + e + 1 < deg) ? r1 : NN;
            r2 = (c + e + 2 < deg) ? r2 : NN;
            r3 = (c + e + 3 < deg) ? r3 : NN;
            uint4 v0 = *(const uint4*)(fb + (size_t)r0 * DF);
            uint4 v1 = *(const uint4*)(fb + (size_t)r1 * DF);
            uint4 v2 = *(const uint4*)(fb + (size_t)r2 * DF);
            uint4 v3 = *(const uint4*)(fb + (size_t)r3 * DF);
            acc[0] += lo_f(v0.x); acc[1] += hi_f(v0.x); acc[2] += lo_f(v0.y); acc[3] += hi_f(v0.y);
            acc[4] += lo_f(v0.z); acc[5] += hi_f(v0.z); acc[6] += lo_f(v0.w); acc[7] += hi_f(v0.w);
            acc[0] += lo_f(v1.x); acc[1] += hi_f(v1.x); acc[2] += lo_f(v1.y); acc[3] += hi_f(v1.y);
            acc[4] += lo_f(v1.z); acc[5] += hi_f(v1.z); acc[6] += lo_f(v1.w); acc[7] += hi_f(v1.w);
            acc[0] += lo_f(v2.x); acc[1] += hi_f(v2.x); acc[2] += lo_f(v2.y); acc[3] += hi_f(v2.y);
            acc[4] += lo_f(v2.z); acc[5] += hi_f(v2.z); acc[6] += lo_f(v2.w); acc[7] += hi_f(v2.w);
            acc[0] += lo_f(v3.x); acc[1] += hi_f(v3.x); acc[2] += lo_f(v3.y); acc[3] += hi_f(v3.y);
            acc[4] += lo_f(v3.z); acc[5] += hi_f(v3.z); acc[6] += lo_f(v3.w); acc[7] += hi_f(v3.w);
        }
        for (; e < lim; ++e) {
            int r = __shfl(my, gbase + e);
            r = (c + e < deg) ? r : NN;
            uint4 v = *(const uint4*)(fb + (size_t)r * DF);
            acc[0] += lo_f(v.x); acc[1] += hi_f(v.x); acc[2] += lo_f(v.y); acc[3] += hi_f(v.y);
            acc[4] += lo_f(v.z); acc[5] += hi_f(v.z); acc[6] += lo_f(v.w); acc[7] += hi_f(v.w);
        }
    }
    float inv = 1.0f / (float)(deg > 0 ? deg : 1);
    uint4 o;
    o.x = pack2(acc[0] * inv, acc[1] * inv);
    o.y = pack2(acc[2] * inv, acc[3] * inv);
    o.z = pack2(acc[4] * inv, acc[5] * inv);
    o.w = pack2(acc[6] * inv, acc[7] * inv);
    *(uint4*)(outm + (size_t)n * DF + l16 * 8) = o;
}

// ---------------------------------------------------------------- FUSED dense GEMMs (h in LDS)
// h = relu([mean|xb] @ [Wl0;Wr0] + b0)  (64x128 tile in LDS)
// [t|r] = h @ [Wl1|Wr1]; t -> bf16 tbuf, r + b1 -> f32 rbuf.  Dense, perfectly balanced.
__global__ __launch_bounds__(256) void k_gemmF(const ushort_t* __restrict__ A0,
                                               const ushort_t* __restrict__ A1,
                                               const ushort_t* __restrict__ pw0,
                                               const float* __restrict__ bl0,
                                               const ushort_t* __restrict__ pw1,
                                               const float* __restrict__ bl1,
                                               ushort_t* __restrict__ tbuf,
                                               float* __restrict__ rbuf) {
    __shared__ ushort_t h_lds[64][136];  // 64 rows x 128 cols, +8 pad
    int warp = threadIdx.x >> 6;
    int lane = threadIdx.x & 63;
    int quad = lane >> 4;
    int l16 = lane & 15;
    int m0 = blockIdx.x * 64 + warp * 16;

    int rowA = m0 + l16;
    if (rowA >= NN) rowA = NN - 1;
    const int kofs = quad * 8;

    f32x4 acc[8];
#pragma unroll
    for (int t = 0; t < 8; t++) acc[t] = (f32x4){0.f, 0.f, 0.f, 0.f};

#pragma unroll
    for (int s = 0; s < 8; s++) {
        const ushort_t* Ab = (s < 4) ? A0 : A1;
        int kk = (s & 3) * 32 + kofs;
        ABFrag a;
        a.u = *(const uint4*)(Ab + (size_t)rowA * DF + kk);
#pragma unroll
        for (int t = 0; t < 8; t++) {
            ABFrag b;
            b.u = *(const uint4*)(pw0 + ((size_t)(s * 8 + t) * 64 + lane) * 8);
            acc[t] = __builtin_amdgcn_mfma_f32_16x16x32_bf16(a.v, b.v, acc[t], 0, 0, 0);
        }
    }
#pragma unroll
    for (int t = 0; t < 8; t++) {
        int col = t * 16 + l16;
        float bv = bl0[col];
#pragma unroll
        for (int r = 0; r < 4; r++)
            h_lds[warp * 16 + quad * 4 + r][col] = f2bf(fmaxf(acc[t][r] + bv, 0.f));
    }
    __syncthreads();

    f32x4 c1[8];
#pragma unroll
    for (int t = 0; t < 8; t++) c1[t] = (f32x4){0.f, 0.f, 0.f, 0.f};
#pragma unroll
    for (int s = 0; s < 4; s++) {
        ABFrag a;
        a.u = *(const uint4*)&h_lds[warp * 16 + l16][s * 32 + kofs];
#pragma unroll
        for (int t = 0; t < 8; t++) {
            ABFrag b;
            b.u = *(const uint4*)(pw1 + ((size_t)(s * 8 + t) * 64 + lane) * 8);
            c1[t] = __builtin_amdgcn_mfma_f32_16x16x32_bf16(a.v, b.v, c1[t], 0, 0, 0);
        }
    }
#pragma unroll
    for (int t = 0; t < 8; t++) {
        int cc = (t & 3) * 16 + l16;
        if (t < 4) {
#pragma unroll
            for (int r = 0; r < 4; r++) {
                int row = m0 + quad * 4 + r;
                if (row < NN) tbuf[(size_t)row * 64 + cc] = f2bf(c1[t][r]);
            }
        } else {
            float bv = bl1[cc];
#pragma unroll
            for (int r = 0; r < 4; r++) {
                int row = m0 + quad * 4 + r;
                if (row < NN) rbuf[(size_t)row * 64 + cc] = c1[t][r] + bv;
            }
        }
    }
    if (blockIdx.x == 0 && threadIdx.x < 32)
        ((uint_t*)(tbuf + (size_t)NN * 64))[threadIdx.x] = 0u;  // zero row NN for agg2 clamp
}

// ---------------------------------------------------------------- layer-1 final: out = mean(gather(t)) + r
// R4 load structure (4 outstanding) + perm; 8 nodes per wave (8-lane groups), t rows 128 B.
__global__ __launch_bounds__(256) void k_agg2(const ushort_t* __restrict__ tbuf,
                                              const float* __restrict__ rbuf,
                                              const int* __restrict__ rs,
                                              const int* __restrict__ esrc,
                                              const int* __restrict__ perm,
                                              float* __restrict__ out) {
    int wv = threadIdx.x >> 6;
    int lane = threadIdx.x & 63;
    int li = lane & 7;
    int gbase = lane & 56;
    int slot = (blockIdx.x * 4 + wv) * 8 + (lane >> 3);  // NN = 3125*32 exactly
    int n = perm[slot];
    int s0 = rs[n];
    int deg = rs[n + 1] - s0;
    if (deg == 0) s0 = 0;
    int md = deg;
    md = max(md, __shfl_xor(md, 8));
    md = max(md, __shfl_xor(md, 16));
    md = max(md, __shfl_xor(md, 32));
    float acc[8] = {0.f, 0.f, 0.f, 0.f, 0.f, 0.f, 0.f, 0.f};
    const ushort_t* fb = tbuf + li * 8;
    int clampIdx = (deg > 0) ? deg - 1 : 0;
    for (int c = 0; c < md; c += 8) {
        int ii = c + li;
        if (ii > clampIdx) ii = clampIdx;
        int my = esrc[s0 + ii];
        int lim = md - c;
        if (lim > 8) lim = 8;
        int e = 0;
        for (; e + 4 <= lim; e += 4) {
            int r0 = __shfl(my, gbase + e);
            int r1 = __shfl(my, gbase + e + 1);
            int r2 = __shfl(my, gbase + e + 2);
            int r3 = __shfl(my, gbase + e + 3);
            r0 = (c + e < deg) ? r0 : NN;
            r1 = (c + e + 1 < deg) ? r1 : NN;
            r2 = (c + e + 2 < deg) ? r2 : NN;
            r3 = (c + e + 3 < deg) ? r3 : NN;
            uint4 v0 = *(const uint4*)(fb + (size_t)r0 * 64);
            uint4 v1 = *(const uint4*)(fb + (size_t)r1 * 64);
            uint4 v2 = *(const uint4*)(fb + (size_t)r2 * 64);
            uint4 v3 = *(const uint4*)(fb + (size_t)r3 * 64);
            acc[0] += lo_f(v0.x); acc[1] += hi_f(v0.x); acc[2] += lo_f(v0.y); acc[3] += hi_f(v0.y);
            acc[4] += lo_f(v0.z); acc[5] += hi_f(v0.z); acc[6] += lo_f(v0.w); acc[7] += hi_f(v0.w);
            acc[0] += lo_f(v1.x); acc[1] += hi_f(v1.x); acc[2] += lo_f(v1.y); acc[3] += hi_f(v1.y);
            acc[4] += lo_f(v1.z); acc[5] += hi_f(v1.z); acc[6] += lo_f(v1.w); acc[7] += hi_f(v1.w);
            acc[0] += lo_f(v2.x); acc[1] += hi_f(v2.x); acc[2] += lo_f(v2.y); acc[3] += hi_f(v2.y);
            acc[4] += lo_f(v2.z); acc[5] += hi_f(v2.z); acc[6] += lo_f(v2.w); acc[7] += hi_f(v2.w);
            acc[0] += lo_f(v3.x); acc[1] += hi_f(v3.x); acc[2] += lo_f(v3.y); acc[3] += hi_f(v3.y);
            acc[4] += lo_f(v3.z); acc[5] += hi_f(v3.z); acc[6] += lo_f(v3.w); acc[7] += hi_f(v3.w);
        }
        for (; e < lim; ++e) {
            int r = __shfl(my, gbase + e);
            r = (c + e < deg) ? r : NN;
            uint4 v = *(const uint4*)(fb + (size_t)r * 64);
            acc[0] += lo_f(v.x); acc[1] += hi_f(v.x); acc[2] += lo_f(v.y); acc[3] += hi_f(v.y);
            acc[4] += lo_f(v.z); acc[5] += hi_f(v.z); acc[6] += lo_f(v.w); acc[7] += hi_f(v.w);
        }
    }
    float inv = 1.0f / (float)(deg > 0 ? deg : 1);
    const float4* rp = (const float4*)(rbuf + (size_t)n * 64 + li * 8);
    float4 ra = rp[0], rb = rp[1];
    float4 oa, ob;
    oa.x = acc[0] * inv + ra.x; oa.y = acc[1] * inv + ra.y;
    oa.z = acc[2] * inv + ra.z; oa.w = acc[3] * inv + ra.w;
    ob.x = acc[4] * inv + rb.x; ob.y = acc[5] * inv + rb.y;
    ob.z = acc[6] * inv + rb.z; ob.w = acc[7] * inv + rb.w;
    float4* op = (float4*)(out + (size_t)n * 64 + li * 8);
    op[0] = oa;
    op[1] = ob;
}

// ---------------------------------------------------------------- launcher
extern "C" void kernel_launch(void* const* d_in, const int* in_sizes, int n_in,
                              void* d_out, int out_size, void* d_ws, size_t ws_size,
                              hipStream_t stream) {
    const float* x   = (const float*)d_in[0];
    const int*   ei  = (const int*)d_in[1];
    const float* Wl0 = (const float*)d_in[2];
    const float* bl0 = (const float*)d_in[3];
    const float* Wr0 = (const float*)d_in[4];
    const float* Wl1 = (const float*)d_in[5];
    const float* bl1 = (const float*)d_in[6];
    const float* Wr1 = (const float*)d_in[7];
    float* out = (float*)d_out;

    char* ws = (char*)d_ws;
    size_t off = 0;
    auto alloc = [&](size_t b) {
        size_t o = off;
        off += (b + 255) & ~(size_t)255;
        return o;
    };
    int* rs      = (int*)(ws + alloc((size_t)(NN + 1) * 4));
    int* M       = (int*)(ws + alloc((size_t)NBKT * 256 * 4));
    int* colsum  = (int*)(ws + alloc((size_t)NBKT * 4));
    int* bkbase  = (int*)(ws + alloc((size_t)(NBKT + 1) * 4));
    int* M2      = (int*)(ws + alloc((size_t)512 * 256 * 4));
    int* colsum2 = (int*)(ws + alloc((size_t)512 * 4));
    int* dbase   = (int*)(ws + alloc((size_t)512 * 4));
    int* perm    = (int*)(ws + alloc((size_t)NN * 4));
    int* esrc    = (int*)(ws + alloc((size_t)NE * 4));
    ushort_t* pw0  = (ushort_t*)(ws + alloc((size_t)8 * 8 * 512 * 2));
    ushort_t* pw1  = (ushort_t*)(ws + alloc((size_t)4 * 8 * 512 * 2));
    ushort_t* xb   = (ushort_t*)(ws + alloc((size_t)(NN + 1) * DF * 2));  // +1 zero row
    ushort_t* mean = (ushort_t*)(ws + alloc((size_t)NN * DF * 2));
    ushort_t* tbuf = (ushort_t*)(ws + alloc((size_t)(NN + 1) * 64 * 2));  // +1 zero row
    float*    rbuf = (float*)(ws + alloc((size_t)NN * 64 * 4));
    // tmp (12.8MB, bktscatter->bktsort) aliases mean (25.6MB, first written by k_agg0 later)
    uint2* tmp = (uint2*)mean;

    k_bktcnt<<<256, 256, 0, stream>>>(ei, M);
    k_colscan<<<NBKT, 256, 0, stream>>>(M, colsum);
    k_bktscan<<<1, 256, 0, stream>>>(colsum, bkbase, rs);
    k_bktscatter<<<256, 256, 0, stream>>>(ei, M, bkbase, tmp);
    k_bktsort<<<NBKT, 256, 0, stream>>>(tmp, bkbase, rs, esrc);
    k_dcnt<<<256, 256, 0, stream>>>(rs, M2);
    k_colscan<<<512, 256, 0, stream>>>(M2, colsum2);
    k_scan512<<<1, 512, 0, stream>>>(colsum2, dbase);
    k_dperm<<<256, 256, 0, stream>>>(rs, M2, dbase, perm);
    k_prep<<<CAST_B + 128 + 64, 256, 0, stream>>>(x, xb, Wl0, Wr0, pw0, Wl1, Wr1, pw1);

    k_agg0<<<NN / 16, 256, 0, stream>>>(xb, rs, esrc, perm, mean);
    k_gemmF<<<(NN + 63) / 64, 256, 0, stream>>>(mean, xb, pw0, bl0, pw1, bl1, tbuf, rbuf);
    k_agg2<<<NN / 32, 256, 0, stream>>>(tbuf, rbuf, rs, esrc, perm, out);
}

// Round 8
// 273.642 us; speedup vs baseline: 1.2389x; 1.1554x over previous
//
#include <hip/hip_runtime.h>
#include <type_traits>

#define NN 100000
#define NE 1600000
#define DF 128
#define NBKT 196        // ceil(100000 / 512) node buckets
#define BKT_SHIFT 9     // 512 nodes per bucket
#define EPB 6250        // edges per block in bucket passes (256 blocks * 6250 = NE)

typedef unsigned short ushort_t;
typedef unsigned int uint_t;
typedef unsigned char uchar_t;
typedef __bf16 bf16x8 __attribute__((ext_vector_type(8)));
typedef float f32x4 __attribute__((ext_vector_type(4)));
typedef float f32x2 __attribute__((ext_vector_type(2)));

union ABFrag { uint4 u; bf16x8 v; ushort_t s[8]; };

__device__ __forceinline__ ushort_t f2bf(float f) {
    uint_t u;
    __builtin_memcpy(&u, &f, 4);
    uint_t rounding = 0x7FFFu + ((u >> 16) & 1u);
    u += rounding;
    return (ushort_t)(u >> 16);
}
__device__ __forceinline__ float lo_f(uint_t u) { return __uint_as_float(u << 16); }
__device__ __forceinline__ float hi_f(uint_t u) { return __uint_as_float(u & 0xffff0000u); }
__device__ __forceinline__ uint_t pack2(float a, float b) {
    return (uint_t)f2bf(a) | ((uint_t)f2bf(b) << 16);
}

// is64 detection, inlined per block (wave 0 checks odd words of first 64 ints)
__device__ __forceinline__ int detect64(const int* ei, int* s64) {
    if (threadIdx.x < 64) {
        int v = ei[threadIdx.x];
        bool ok = ((threadIdx.x & 1) == 0) || (v == 0);
        unsigned long long m = __ballot(ok);
        if (threadIdx.x == 0) *s64 = (m == 0xFFFFFFFFFFFFFFFFULL) ? 1 : 0;
    }
    __syncthreads();
    return *s64;
}

// ---------------------------------------------------------------- pass A: per-(block,bucket) histogram
__global__ __launch_bounds__(256) void k_bktcnt(const int* __restrict__ ei,
                                                int* __restrict__ M) {
    __shared__ int cnt[NBKT];
    __shared__ int s64;
    int t = threadIdx.x, blk = blockIdx.x;
    int is64 = detect64(ei, &s64);
    for (int i = t; i < NBKT; i += 256) cnt[i] = 0;
    __syncthreads();
    int e0 = blk * EPB;
    if (is64) {
        const long long* p = (const long long*)ei;
        for (int i = t; i < EPB; i += 256) {
            int d = (int)p[(size_t)NE + e0 + i];
            atomicAdd(&cnt[d >> BKT_SHIFT], 1);
        }
    } else {
        for (int i = t; i < EPB; i += 256) {
            int d = ei[NE + e0 + i];
            atomicAdd(&cnt[d >> BKT_SHIFT], 1);
        }
    }
    __syncthreads();
    for (int i = t; i < NBKT; i += 256) M[i * 256 + blk] = cnt[i];
}

// ---------------------------------------------------------------- per-bucket column scan over 256 blocks
__global__ __launch_bounds__(256) void k_colscan(int* __restrict__ M, int* __restrict__ colsum) {
    __shared__ int sm[256];
    int t = threadIdx.x, b = blockIdx.x;
    int v = M[b * 256 + t];
    sm[t] = v;
    __syncthreads();
    for (int o = 1; o < 256; o <<= 1) {
        int add = (t >= o) ? sm[t - o] : 0;
        __syncthreads();
        sm[t] += add;
        __syncthreads();
    }
    M[b * 256 + t] = sm[t] - v;  // exclusive offset of block t within bucket b
    if (t == 255) colsum[b] = sm[255];
}

// ---------------------------------------------------------------- scan bucket totals -> bkbase[0..NBKT]
__global__ __launch_bounds__(256) void k_bktscan(const int* __restrict__ colsum,
                                                 int* __restrict__ bkbase, int* __restrict__ rs) {
    __shared__ int sm[256];
    int t = threadIdx.x;
    int v = (t < NBKT) ? colsum[t] : 0;
    sm[t] = v;
    __syncthreads();
    for (int o = 1; o < 256; o <<= 1) {
        int add = (t >= o) ? sm[t - o] : 0;
        __syncthreads();
        sm[t] += add;
        __syncthreads();
    }
    if (t <= NBKT) bkbase[t] = sm[t] - v;  // exclusive; bkbase[NBKT] == NE
    if (t == 0) rs[NN] = NE;
}

// ---------------------------------------------------------------- pass B: scatter packed (src|ldst) into buckets
// pk = src | (localdst << 17); src < 2^17, localdst < 512.
__global__ __launch_bounds__(256) void k_bktscatter(const int* __restrict__ ei,
                                                    const int* __restrict__ M,
                                                    const int* __restrict__ bkbase,
                                                    uint_t* __restrict__ tmp) {
    __shared__ int cur[NBKT];
    __shared__ int s64;
    int t = threadIdx.x, blk = blockIdx.x;
    int is64 = detect64(ei, &s64);
    for (int i = t; i < NBKT; i += 256) cur[i] = bkbase[i] + M[i * 256 + blk];
    __syncthreads();
    int e0 = blk * EPB;
    if (is64) {
        const long long* p = (const long long*)ei;
        for (int i = t; i < EPB; i += 256) {
            int e = e0 + i;
            int s = (int)p[e], d = (int)p[(size_t)NE + e];
            int pos = atomicAdd(&cur[d >> BKT_SHIFT], 1);
            tmp[pos] = (uint_t)s | ((uint_t)(d & 511) << 17);
        }
    } else {
        for (int i = t; i < EPB; i += 256) {
            int e = e0 + i;
            int s = ei[e], d = ei[NE + e];
            int pos = atomicAdd(&cur[d >> BKT_SHIFT], 1);
            tmp[pos] = (uint_t)s | ((uint_t)(d & 511) << 17);
        }
    }
}

// ---------------------------------------------------------------- pass C: per-bucket node sort -> rs + esrc
__global__ __launch_bounds__(256) void k_bktsort(const uint_t* __restrict__ tmp,
                                                 const int* __restrict__ bkbase,
                                                 int* __restrict__ rs, int* __restrict__ esrc) {
    __shared__ int hist[512];
    __shared__ int curp[512];
    int t = threadIdx.x, b = blockIdx.x;
    int nbase = b << BKT_SHIFT;
    int bb = bkbase[b], be = bkbase[b + 1];
    hist[t] = 0;
    hist[t + 256] = 0;
    __syncthreads();
    for (int i = bb + t; i < be; i += 256)
        atomicAdd(&hist[tmp[i] >> 17], 1);
    __syncthreads();
    int ov0 = hist[t], ov1 = hist[t + 256];
    for (int o = 1; o < 512; o <<= 1) {
        int v0 = (t >= o) ? hist[t - o] : 0;
        int v1 = (t + 256 >= o) ? hist[t + 256 - o] : 0;
        __syncthreads();
        hist[t] += v0;
        hist[t + 256] += v1;
        __syncthreads();
    }
    int ex0 = bb + hist[t] - ov0;
    int ex1 = bb + hist[t + 256] - ov1;
    int n0 = nbase + t, n1 = nbase + t + 256;
    if (n0 < NN) rs[n0] = ex0;
    if (n1 < NN) rs[n1] = ex1;
    curp[t] = ex0;
    curp[t + 256] = ex1;
    __syncthreads();
    for (int i = bb + t; i < be; i += 256) {
        uint_t pk = tmp[i];
        int pos = atomicAdd(&curp[pk >> 17], 1);
        esrc[pos] = (int)(pk & 0x1FFFFu);
    }
}

// ---------------------------------------------------------------- prep: cast x->fp8 x8 (+zero row), pack W0, W1
// blocks [0, CAST_B): fp8 encode (1 uint / thread); then 128 blocks packW0; then 64 blocks packW1.
#define CAST_B 12501
__global__ void k_prep(const float* __restrict__ x, uchar_t* __restrict__ x8,
                       const float* __restrict__ Wl0, const float* __restrict__ Wr0,
                       ushort_t* __restrict__ pw0,
                       const float* __restrict__ Wl1, const float* __restrict__ Wr1,
                       ushort_t* __restrict__ pw1) {
    const int n4 = NN * DF / 4;  // 3.2M quads
    int blk = blockIdx.x, t = threadIdx.x;
    if (blk < CAST_B) {
        int i = blk * 256 + t;
        if (i < n4) {
            float4 f = ((const float4*)x)[i];
            int lo = __builtin_amdgcn_cvt_pk_fp8_f32(f.x, f.y, 0, false);
            int u = __builtin_amdgcn_cvt_pk_fp8_f32(f.z, f.w, lo, true);
            ((uint_t*)x8)[i] = (uint_t)u;
        } else if (i < n4 + 32) {
            ((uint_t*)x8)[i] = 0u;  // zero row NN (gather clamp target)
        }
    } else if (blk < CAST_B + 128) {
        int idx = (blk - CAST_B) * 256 + t;  // < 32768
        int j = idx & 7;
        int lane = (idx >> 3) & 63;
        int rem = idx / 512;
        int tt = rem % 8;
        int s = rem / 8;
        int quad = lane >> 4, l16 = lane & 15;
        int k = (s & 3) * 32 + quad * 8 + j;
        int n = tt * 16 + l16;
        const float* W = (s < 4) ? Wl0 : Wr0;
        pw0[idx] = f2bf(W[k * 128 + n]);
    } else {
        int idx = (blk - CAST_B - 128) * 256 + t;  // < 16384
        int j = idx & 7;
        int lane = (idx >> 3) & 63;
        int rem = idx / 512;
        int tt = rem % 8;
        int s = rem / 8;
        int quad = lane >> 4, l16 = lane & 15;
        int k = s * 32 + quad * 8 + j;
        int n = (tt & 3) * 16 + l16;
        const float* W = (tt < 4) ? Wl1 : Wr1;
        pw1[idx] = f2bf(W[k * 64 + n]);
    }
}

// ---------------------------------------------------------------- layer-0 mean aggregation (fp8 rows, 128 B)
// 4 nodes per wave (16-lane groups); lane li holds features li*8..li*8+7 (uint2 = 8 fp8).
// x8 row NN is zero. Output mean in bf16.
__global__ __launch_bounds__(256) void k_agg0(const uchar_t* __restrict__ x8,
                                              const int* __restrict__ rs,
                                              const int* __restrict__ esrc,
                                              ushort_t* __restrict__ outm) {
    int wv = threadIdx.x >> 6;
    int lane = threadIdx.x & 63;
    int l16 = lane & 15, gbase = lane & 48;
    int n = (blockIdx.x * 4 + wv) * 4 + (lane >> 4);  // NN = 6250*16 exactly
    int s0 = rs[n];
    int deg = rs[n + 1] - s0;
    if (deg == 0) s0 = 0;
    int md = deg;
    md = max(md, __shfl_xor(md, 16));
    md = max(md, __shfl_xor(md, 32));
    float acc[8] = {0.f, 0.f, 0.f, 0.f, 0.f, 0.f, 0.f, 0.f};
    const uchar_t* fb = x8 + l16 * 8;
    int clampIdx = (deg > 0) ? deg - 1 : 0;
    for (int c = 0; c < md; c += 16) {
        int ii = c + l16;
        if (ii > clampIdx) ii = clampIdx;
        int my = esrc[s0 + ii];
        int lim = md - c;
        if (lim > 16) lim = 16;
        int e = 0;
        for (; e + 4 <= lim; e += 4) {
            int r0 = __shfl(my, gbase + e);
            int r1 = __shfl(my, gbase + e + 1);
            int r2 = __shfl(my, gbase + e + 2);
            int r3 = __shfl(my, gbase + e + 3);
            r0 = (c + e < deg) ? r0 : NN;
            r1 = (c + e + 1 < deg) ? r1 : NN;
            r2 = (c + e + 2 < deg) ? r2 : NN;
            r3 = (c + e + 3 < deg) ? r3 : NN;
            uint2 v0 = *(const uint2*)(fb + (size_t)r0 * DF);
            uint2 v1 = *(const uint2*)(fb + (size_t)r1 * DF);
            uint2 v2 = *(const uint2*)(fb + (size_t)r2 * DF);
            uint2 v3 = *(const uint2*)(fb + (size_t)r3 * DF);
#pragma unroll
            for (int q = 0; q < 4; q++) {
                uint2 v = (q == 0) ? v0 : (q == 1) ? v1 : (q == 2) ? v2 : v3;
                f32x2 p0 = __builtin_amdgcn_cvt_pk_f32_fp8(v.x, false);
                f32x2 p1 = __builtin_amdgcn_cvt_pk_f32_fp8(v.x, true);
                f32x2 p2 = __builtin_amdgcn_cvt_pk_f32_fp8(v.y, false);
                f32x2 p3 = __builtin_amdgcn_cvt_pk_f32_fp8(v.y, true);
                acc[0] += p0.x; acc[1] += p0.y; acc[2] += p1.x; acc[3] += p1.y;
                acc[4] += p2.x; acc[5] += p2.y; acc[6] += p3.x; acc[7] += p3.y;
            }
        }
        for (; e < lim; ++e) {
            int r = __shfl(my, gbase + e);
            r = (c + e < deg) ? r : NN;
            uint2 v = *(const uint2*)(fb + (size_t)r * DF);
            f32x2 p0 = __builtin_amdgcn_cvt_pk_f32_fp8(v.x, false);
            f32x2 p1 = __builtin_amdgcn_cvt_pk_f32_fp8(v.x, true);
            f32x2 p2 = __builtin_amdgcn_cvt_pk_f32_fp8(v.y, false);
            f32x2 p3 = __builtin_amdgcn_cvt_pk_f32_fp8(v.y, true);
            acc[0] += p0.x; acc[1] += p0.y; acc[2] += p1.x; acc[3] += p1.y;
            acc[4] += p2.x; acc[5] += p2.y; acc[6] += p3.x; acc[7] += p3.y;
        }
    }
    float inv = 1.0f / (float)(deg > 0 ? deg : 1);
    uint4 o;
    o.x = pack2(acc[0] * inv, acc[1] * inv);
    o.y = pack2(acc[2] * inv, acc[3] * inv);
    o.z = pack2(acc[4] * inv, acc[5] * inv);
    o.w = pack2(acc[6] * inv, acc[7] * inv);
    *(uint4*)(outm + (size_t)n * DF + l16 * 8) = o;
}

// ---------------------------------------------------------------- FUSED dense GEMMs (h in LDS)
// h = relu([mean | x(bf16-cvt)] @ [Wl0;Wr0] + b0);  [t|r] = h @ [Wl1|Wr1].
// A1 (root path) reads f32 x directly, converts to bf16 frags in-register.
__global__ __launch_bounds__(256) void k_gemmF(const ushort_t* __restrict__ A0,
                                               const float* __restrict__ x,
                                               const ushort_t* __restrict__ pw0,
                                               const float* __restrict__ bl0,
                                               const ushort_t* __restrict__ pw1,
                                               const float* __restrict__ bl1,
                                               ushort_t* __restrict__ tbuf,
                                               float* __restrict__ rbuf) {
    __shared__ ushort_t h_lds[64][136];  // 64 rows x 128 cols, +8 pad
    int warp = threadIdx.x >> 6;
    int lane = threadIdx.x & 63;
    int quad = lane >> 4;
    int l16 = lane & 15;
    int m0 = blockIdx.x * 64 + warp * 16;

    int rowA = m0 + l16;
    if (rowA >= NN) rowA = NN - 1;
    const int kofs = quad * 8;

    f32x4 acc[8];
#pragma unroll
    for (int t = 0; t < 8; t++) acc[t] = (f32x4){0.f, 0.f, 0.f, 0.f};

#pragma unroll
    for (int s = 0; s < 8; s++) {
        int kk = (s & 3) * 32 + kofs;
        ABFrag a;
        if (s < 4) {
            a.u = *(const uint4*)(A0 + (size_t)rowA * DF + kk);
        } else {
            const float* xr = x + (size_t)rowA * DF + kk;
            float4 fa = *(const float4*)xr;
            float4 fc = *(const float4*)(xr + 4);
            a.u.x = pack2(fa.x, fa.y);
            a.u.y = pack2(fa.z, fa.w);
            a.u.z = pack2(fc.x, fc.y);
            a.u.w = pack2(fc.z, fc.w);
        }
#pragma unroll
        for (int t = 0; t < 8; t++) {
            ABFrag b;
            b.u = *(const uint4*)(pw0 + ((size_t)(s * 8 + t) * 64 + lane) * 8);
            acc[t] = __builtin_amdgcn_mfma_f32_16x16x32_bf16(a.v, b.v, acc[t], 0, 0, 0);
        }
    }
#pragma unroll
    for (int t = 0; t < 8; t++) {
        int col = t * 16 + l16;
        float bv = bl0[col];
#pragma unroll
        for (int r = 0; r < 4; r++)
            h_lds[warp * 16 + quad * 4 + r][col] = f2bf(fmaxf(acc[t][r] + bv, 0.f));
    }
    __syncthreads();

    f32x4 c1[8];
#pragma unroll
    for (int t = 0; t < 8; t++) c1[t] = (f32x4){0.f, 0.f, 0.f, 0.f};
#pragma unroll
    for (int s = 0; s < 4; s++) {
        ABFrag a;
        a.u = *(const uint4*)&h_lds[warp * 16 + l16][s * 32 + kofs];
#pragma unroll
        for (int t = 0; t < 8; t++) {
            ABFrag b;
            b.u = *(const uint4*)(pw1 + ((size_t)(s * 8 + t) * 64 + lane) * 8);
            c1[t] = __builtin_amdgcn_mfma_f32_16x16x32_bf16(a.v, b.v, c1[t], 0, 0, 0);
        }
    }
#pragma unroll
    for (int t = 0; t < 8; t++) {
        int cc = (t & 3) * 16 + l16;
        if (t < 4) {
#pragma unroll
            for (int r = 0; r < 4; r++) {
                int row = m0 + quad * 4 + r;
                if (row < NN) tbuf[(size_t)row * 64 + cc] = f2bf(c1[t][r]);
            }
        } else {
            float bv = bl1[cc];
#pragma unroll
            for (int r = 0; r < 4; r++) {
                int row = m0 + quad * 4 + r;
                if (row < NN) rbuf[(size_t)row * 64 + cc] = c1[t][r] + bv;
            }
        }
    }
    if (blockIdx.x == 0 && threadIdx.x < 32)
        ((uint_t*)(tbuf + (size_t)NN * 64))[threadIdx.x] = 0u;  // zero row NN for agg2 clamp
}

// ---------------------------------------------------------------- layer-1 final: out = mean(gather(t)) + r
// 8 nodes per wave (8-lane groups); t rows 128 B bf16; 4 outstanding loads.
__global__ __launch_bounds__(256) void k_agg2(const ushort_t* __restrict__ tbuf,
                                              const float* __restrict__ rbuf,
                                              const int* __restrict__ rs,
                                              const int* __restrict__ esrc,
                                              float* __restrict__ out) {
    int wv = threadIdx.x >> 6;
    int lane = threadIdx.x & 63;
    int li = lane & 7;
    int gbase = lane & 56;
    int n = (blockIdx.x * 4 + wv) * 8 + (lane >> 3);  // NN = 3125*32 exactly
    int s0 = rs[n];
    int deg = rs[n + 1] - s0;
    if (deg == 0) s0 = 0;
    int md = deg;
    md = max(md, __shfl_xor(md, 8));
    md = max(md, __shfl_xor(md, 16));
    md = max(md, __shfl_xor(md, 32));
    float acc[8] = {0.f, 0.f, 0.f, 0.f, 0.f, 0.f, 0.f, 0.f};
    const ushort_t* fb = tbuf + li * 8;
    int clampIdx = (deg > 0) ? deg - 1 : 0;
    for (int c = 0; c < md; c += 8) {
        int ii = c + li;
        if (ii > clampIdx) ii = clampIdx;
        int my = esrc[s0 + ii];
        int lim = md - c;
        if (lim > 8) lim = 8;
        int e = 0;
        for (; e + 4 <= lim; e += 4) {
            int r0 = __shfl(my, gbase + e);
            int r1 = __shfl(my, gbase + e + 1);
            int r2 = __shfl(my, gbase + e + 2);
            int r3 = __shfl(my, gbase + e + 3);
            r0 = (c + e < deg) ? r0 : NN;
            r1 = (c + e + 1 < deg) ? r1 : NN;
            r2 = (c + e + 2 < deg) ? r2 : NN;
            r3 = (c + e + 3 < deg) ? r3 : NN;
            uint4 v0 = *(const uint4*)(fb + (size_t)r0 * 64);
            uint4 v1 = *(const uint4*)(fb + (size_t)r1 * 64);
            uint4 v2 = *(const uint4*)(fb + (size_t)r2 * 64);
            uint4 v3 = *(const uint4*)(fb + (size_t)r3 * 64);
            acc[0] += lo_f(v0.x); acc[1] += hi_f(v0.x); acc[2] += lo_f(v0.y); acc[3] += hi_f(v0.y);
            acc[4] += lo_f(v0.z); acc[5] += hi_f(v0.z); acc[6] += lo_f(v0.w); acc[7] += hi_f(v0.w);
            acc[0] += lo_f(v1.x); acc[1] += hi_f(v1.x); acc[2] += lo_f(v1.y); acc[3] += hi_f(v1.y);
            acc[4] += lo_f(v1.z); acc[5] += hi_f(v1.z); acc[6] += lo_f(v1.w); acc[7] += hi_f(v1.w);
            acc[0] += lo_f(v2.x); acc[1] += hi_f(v2.x); acc[2] += lo_f(v2.y); acc[3] += hi_f(v2.y);
            acc[4] += lo_f(v2.z); acc[5] += hi_f(v2.z); acc[6] += lo_f(v2.w); acc[7] += hi_f(v2.w);
            acc[0] += lo_f(v3.x); acc[1] += hi_f(v3.x); acc[2] += lo_f(v3.y); acc[3] += hi_f(v3.y);
            acc[4] += lo_f(v3.z); acc[5] += hi_f(v3.z); acc[6] += lo_f(v3.w); acc[7] += hi_f(v3.w);
        }
        for (; e < lim; ++e) {
            int r = __shfl(my, gbase + e);
            r = (c + e < deg) ? r : NN;
            uint4 v = *(const uint4*)(fb + (size_t)r * 64);
            acc[0] += lo_f(v.x); acc[1] += hi_f(v.x); acc[2] += lo_f(v.y); acc[3] += hi_f(v.y);
            acc[4] += lo_f(v.z); acc[5] += hi_f(v.z); acc[6] += lo_f(v.w); acc[7] += hi_f(v.w);
        }
    }
    float inv = 1.0f / (float)(deg > 0 ? deg : 1);
    const float4* rp = (const float4*)(rbuf + (size_t)n * 64 + li * 8);
    float4 ra = rp[0], rb = rp[1];
    float4 oa, ob;
    oa.x = acc[0] * inv + ra.x; oa.y = acc[1] * inv + ra.y;
    oa.z = acc[2] * inv + ra.z; oa.w = acc[3] * inv + ra.w;
    ob.x = acc[4] * inv + rb.x; ob.y = acc[5] * inv + rb.y;
    ob.z = acc[6] * inv + rb.z; ob.w = acc[7] * inv + rb.w;
    float4* op = (float4*)(out + (size_t)n * 64 + li * 8);
    op[0] = oa;
    op[1] = ob;
}

// ---------------------------------------------------------------- launcher
extern "C" void kernel_launch(void* const* d_in, const int* in_sizes, int n_in,
                              void* d_out, int out_size, void* d_ws, size_t ws_size,
                              hipStream_t stream) {
    const float* x   = (const float*)d_in[0];
    const int*   ei  = (const int*)d_in[1];
    const float* Wl0 = (const float*)d_in[2];
    const float* bl0 = (const float*)d_in[3];
    const float* Wr0 = (const float*)d_in[4];
    const float* Wl1 = (const float*)d_in[5];
    const float* bl1 = (const float*)d_in[6];
    const float* Wr1 = (const float*)d_in[7];
    float* out = (float*)d_out;

    char* ws = (char*)d_ws;
    size_t off = 0;
    auto alloc = [&](size_t b) {
        size_t o = off;
        off += (b + 255) & ~(size_t)255;
        return o;
    };
    int* rs     = (int*)(ws + alloc((size_t)(NN + 1) * 4));
    int* M      = (int*)(ws + alloc((size_t)NBKT * 256 * 4));
    int* colsum = (int*)(ws + alloc((size_t)NBKT * 4));
    int* bkbase = (int*)(ws + alloc((size_t)(NBKT + 1) * 4));
    int* esrc   = (int*)(ws + alloc((size_t)NE * 4));
    ushort_t* pw0  = (ushort_t*)(ws + alloc((size_t)8 * 8 * 512 * 2));
    ushort_t* pw1  = (ushort_t*)(ws + alloc((size_t)4 * 8 * 512 * 2));
    uchar_t*  x8   = (uchar_t*)(ws + alloc((size_t)(NN + 1) * DF));      // fp8, +1 zero row
    ushort_t* mean = (ushort_t*)(ws + alloc((size_t)NN * DF * 2));
    ushort_t* tbuf = (ushort_t*)(ws + alloc((size_t)(NN + 1) * 64 * 2)); // +1 zero row
    float*    rbuf = (float*)(ws + alloc((size_t)NN * 64 * 4));
    // tmp (6.4MB, bktscatter->bktsort) aliases mean (25.6MB, first written by k_agg0 later)
    uint_t* tmp = (uint_t*)mean;

    k_bktcnt<<<256, 256, 0, stream>>>(ei, M);
    k_colscan<<<NBKT, 256, 0, stream>>>(M, colsum);
    k_bktscan<<<1, 256, 0, stream>>>(colsum, bkbase, rs);
    k_bktscatter<<<256, 256, 0, stream>>>(ei, M, bkbase, tmp);
    k_bktsort<<<NBKT, 256, 0, stream>>>(tmp, bkbase, rs, esrc);
    k_prep<<<CAST_B + 128 + 64, 256, 0, stream>>>(x, x8, Wl0, Wr0, pw0, Wl1, Wr1, pw1);

    k_agg0<<<NN / 16, 256, 0, stream>>>(x8, rs, esrc, mean);
    k_gemmF<<<(NN + 63) / 64, 256, 0, stream>>>(mean, x, pw0, bl0, pw1, bl1, tbuf, rbuf);
    k_agg2<<<NN / 32, 256, 0, stream>>>(tbuf, rbuf, rs, esrc, out);
}